// Round 21
// baseline (236.326 us; speedup 1.0000x reference)
//
#include <hip/hip_runtime.h>
#include <hip/hip_fp16.h>
#include <hip/hip_fp8.h>

#define N_NODES 100000
#define N_EDGES 3200000
#define N_FEAT  128
#define DIM     48
#define N_CLASS 18
#define BN_EPS  1e-5f

#define PADW 136   // f16 MFMA K=128 tile row stride
#define PADC 72    // f16 MFMA K=64 tile row stride
#define MB8  64    // fp8 message-row stride in BYTES (48B payload, 64B aligned)

#define BSH    8                                   // bucket = dst >> 8 (256 nodes)
#define BROWS  256
#define NBUCK  ((N_NODES + BROWS - 1) / BROWS)     // 391
#define BCAP   9216
#define EPB    4096
#define NBLK_E ((N_EDGES + EPB - 1) / EPB)         // 782
#define EPT    36                                  // edges per thread reg-cache (36*256 = BCAP)

#define NB64   ((N_NODES + 63) / 64)               // 1563

typedef __attribute__((ext_vector_type(8))) _Float16 f16x8;
typedef __attribute__((ext_vector_type(4))) float f32x4;

// packed edge: (src << 8) | (dst & 255)  — src < 2^17, fits 25 bits

__device__ __forceinline__ unsigned char f32tof8(float v) {
    __hip_fp8_e4m3 h(v);
    return (unsigned char)h.__x;
}
__device__ __forceinline__ float f8tof32(unsigned char b) {
    __hip_fp8_e4m3 h; h.__x = (__hip_fp8_storage_t)b;
    return (float)h;
}

// ---------------- binning: direct scatter into slack bucket windows ----------------

__global__ __launch_bounds__(256) void k_bin(const int* __restrict__ ei,
                                             int* __restrict__ bcursor,
                                             unsigned int* __restrict__ pairs) {
    __shared__ int h[NBUCK];
    __shared__ int pos[NBUCK];
    const int t = threadIdx.x;
    const int bs = blockIdx.x * EPB;
    const int ce = min(EPB, N_EDGES - bs);

    int sv[16], dv[16];
    #pragma unroll
    for (int i = 0; i < 16; i++) {
        int e = t + i * 256;
        if (e < ce) { sv[i] = ei[bs + e]; dv[i] = ei[N_EDGES + bs + e]; }
        else { sv[i] = 0; dv[i] = -1; }
    }
    for (int i = t; i < NBUCK; i += 256) h[i] = 0;
    __syncthreads();
    #pragma unroll
    for (int i = 0; i < 16; i++)
        if (dv[i] >= 0) atomicAdd(&h[dv[i] >> BSH], 1);
    __syncthreads();

    for (int b = t; b < NBUCK; b += 256) {
        int cnt = h[b];
        if (cnt > 0) {
            int g = atomicAdd(&bcursor[b], cnt);
            h[b] = b * BCAP + g;
        }
        pos[b] = 0;
    }
    __syncthreads();

    #pragma unroll
    for (int i = 0; i < 16; i++) {
        if (dv[i] >= 0) {
            int b = dv[i] >> BSH;
            int p = atomicAdd(&pos[b], 1);
            pairs[h[b] + p] = ((unsigned int)sv[i] << 8) | (unsigned int)(dv[i] & (BROWS - 1));
        }
    }
}

// ---------------- fused: per-bucket counting sort (blocks 0..390) + conv1-front MFMA ----------------
// Sort: ONE global read of pairs (reg-cached, EPT=36/thread), LDS-staged scatter,
// linear coalesced copy-out.

__global__ __launch_bounds__(256) void k_sortg1(const unsigned int* __restrict__ pairs,
                                                const int* __restrict__ bcursor,
                                                int* __restrict__ row_beg,
                                                int* __restrict__ row_end,
                                                int* __restrict__ sorted_src,
                                                const float* __restrict__ x,
                                                const float* __restrict__ W1,
                                                __half* __restrict__ t1,
                                                unsigned char* __restrict__ t2f8) {
    __shared__ __align__(16) char smem[47104];
    const int t = threadIdx.x;

    if (blockIdx.x < NBUCK) {
        int* histw = (int*)smem;                  // 4*BROWS = 4096 B
        int* woff  = (int*)(smem + 4096);         // 4096 B
        int* scn   = (int*)(smem + 8192);         // 1024 B
        int* beg   = (int*)(smem + 9216);         // 1024 B
        int* stage = (int*)(smem + 10240);        // BCAP*4 = 36864 B
        const int wid = t >> 6;
        const int b = blockIdx.x;
        const int nbase = b << BSH;
        const int start_w = b * BCAP;
        const int cnt = bcursor[b];

        unsigned int pr[EPT];
        #pragma unroll
        for (int i = 0; i < EPT; i++) {
            int e = t + i * 256;
            pr[i] = (e < cnt) ? pairs[start_w + e] : 0xFFFFFFFFu;
        }
        for (int i = t; i < 4 * BROWS; i += 256) histw[i] = 0;
        __syncthreads();
        #pragma unroll
        for (int i = 0; i < EPT; i++)
            if (pr[i] != 0xFFFFFFFFu)
                atomicAdd(&histw[wid * BROWS + (int)(pr[i] & (BROWS - 1))], 1);
        __syncthreads();

        int run = 0;
        #pragma unroll
        for (int w = 0; w < 4; w++) {
            woff[w * BROWS + t] = run;
            run += histw[w * BROWS + t];
        }
        int tot = run;
        scn[t] = tot;
        __syncthreads();
        for (int off = 1; off < BROWS; off <<= 1) {
            int v = (t >= off) ? scn[t - off] : 0;
            __syncthreads();
            scn[t] += v;
            __syncthreads();
        }
        int rb = scn[t] - tot;
        beg[t] = rb;
        {
            int n = nbase + t;
            if (n < N_NODES) {
                row_beg[n] = start_w + rb;
                row_end[n] = start_w + rb + tot;
            }
        }
        __syncthreads();
        #pragma unroll
        for (int w = 0; w < 4; w++)
            histw[w * BROWS + t] = beg[t] + woff[w * BROWS + t];
        __syncthreads();
        #pragma unroll
        for (int i = 0; i < EPT; i++) {
            if (pr[i] != 0xFFFFFFFFu) {
                int node = (int)(pr[i] & (BROWS - 1));
                int idx = atomicAdd(&histw[wid * BROWS + node], 1);
                stage[idx] = (int)(pr[i] >> 8);
            }
        }
        __syncthreads();
        for (int i = t; i < cnt; i += 256)
            sorted_src[start_w + i] = stage[i];
    } else {
        // ---- g1 body: t1 = x@W1 (fp16), msgs = relu(x)@W1 (fp8) ----
        _Float16* sX = (_Float16*)smem;                        // 64*PADW*2 = 17408 B
        _Float16* sW = (_Float16*)(smem + 64 * PADW * 2);      // 48*PADW*2 = 13056 B
        const int base = (blockIdx.x - NBUCK) * 64;
        const int wid = t >> 6, lane = t & 63;

        for (int idx = t; idx < DIM * (N_FEAT / 2); idx += 256) {
            int c = idx >> 6;
            int kk = (idx & 63) * 2;
            *(__half2*)&sW[c * PADW + kk] =
                __floats2half2_rn(W1[kk * DIM + c], W1[(kk + 1) * DIM + c]);
        }
        #pragma unroll
        for (int i = 0; i < 8; i++) {
            int idx = t + i * 256;
            int row = idx >> 5, kq = idx & 31;
            float4 v = make_float4(0.f, 0.f, 0.f, 0.f);
            if (base + row < N_NODES) v = ((const float4*)x)[(base + row) * 32 + kq];
            *(__half2*)&sX[row * PADW + kq * 4]     = __floats2half2_rn(v.x, v.y);
            *(__half2*)&sX[row * PADW + kq * 4 + 2] = __floats2half2_rn(v.z, v.w);
        }
        __syncthreads();

        const int r16 = wid * 16;
        const int lrow = lane & 15;
        const int lk = (lane >> 4) * 8;

        f32x4 acc1[3], acc2[3];
        #pragma unroll
        for (int c = 0; c < 3; c++) {
            acc1[c] = (f32x4){0.f, 0.f, 0.f, 0.f};
            acc2[c] = (f32x4){0.f, 0.f, 0.f, 0.f};
        }

        #pragma unroll
        for (int ks = 0; ks < 4; ks++) {
            f16x8 a = *(const f16x8*)&sX[(r16 + lrow) * PADW + ks * 32 + lk];
            f16x8 ra;
            #pragma unroll
            for (int j = 0; j < 8; j++)
                ra[j] = a[j] > (_Float16)0 ? a[j] : (_Float16)0;
            #pragma unroll
            for (int c = 0; c < 3; c++) {
                f16x8 b = *(const f16x8*)&sW[(c * 16 + lrow) * PADW + ks * 32 + lk];
                acc1[c] = __builtin_amdgcn_mfma_f32_16x16x32_f16(a,  b, acc1[c], 0, 0, 0);
                acc2[c] = __builtin_amdgcn_mfma_f32_16x16x32_f16(ra, b, acc2[c], 0, 0, 0);
            }
        }

        const int orow = r16 + (lane >> 4) * 4;
        const int ocol = lane & 15;
        #pragma unroll
        for (int q = 0; q < 4; q++) {
            int gr = base + orow + q;
            if (gr < N_NODES) {
                #pragma unroll
                for (int c = 0; c < 3; c++) {
                    t1[gr * DIM + c * 16 + ocol] = __float2half(acc1[c][q]);
                    t2f8[(size_t)gr * MB8 + c * 16 + ocol] = f32tof8(acc2[c][q]);
                }
            }
        }
    }
}

// ---------------- aggregation: u = relu(tlin + segsum(msg_fp8) + bias) ----------------
// 21 nodes/wave: 3 lanes/node, 16B (16 fp8 feats) per lane -> 2x nodes and
// lines in flight vs 10/wave, half the VMEM instructions per edge.
// out aliases tlin (read-before-write, same thread, row-exclusive).

__device__ inline float2 h2tof2(unsigned int u) {
    __half2 h = *reinterpret_cast<__half2*>(&u);
    return __half22float2(h);
}

__device__ __forceinline__ void accf8q(unsigned int w, float* a) {
    a[0] += f8tof32((unsigned char)(w));
    a[1] += f8tof32((unsigned char)(w >> 8));
    a[2] += f8tof32((unsigned char)(w >> 16));
    a[3] += f8tof32((unsigned char)(w >> 24));
}

__device__ __forceinline__ void acc16(uint4 v, float* a) {
    accf8q(v.x, a);
    accf8q(v.y, a + 4);
    accf8q(v.z, a + 8);
    accf8q(v.w, a + 12);
}

__global__ __launch_bounds__(256) void k_aggr(const uint4* tl4,                  // fp16 [N][6] 16B chunks
                                              const uint4* __restrict__ msg4,    // fp8 [N][4] 16B chunks
                                              const int* __restrict__ row_beg,
                                              const int* __restrict__ row_end,
                                              const int* __restrict__ ssrc,
                                              const float* __restrict__ bias,
                                              uint4* out4) {
    const int t = threadIdx.x;
    const int wid = t >> 6, lane = t & 63;
    const int sub = lane / 3;           // 0..21 (21 = idle lane 63)
    const int fl  = lane - sub * 3;     // 0..2 -> feats fl*16 .. fl*16+15
    int n = blockIdx.x * 84 + wid * 21 + sub;
    const bool act = (sub < 21) && (n < N_NODES);
    int start = 0, end = 0;
    if (act) { start = row_beg[n]; end = row_end[n]; }

    float a[16];
    #pragma unroll
    for (int i = 0; i < 16; i++) a[i] = 0.f;

    int e = start;
    for (; e + 8 <= end; e += 8) {
        int s0 = ssrc[e], s1 = ssrc[e + 1], s2 = ssrc[e + 2], s3 = ssrc[e + 3];
        int s4 = ssrc[e + 4], s5 = ssrc[e + 5], s6 = ssrc[e + 6], s7 = ssrc[e + 7];
        uint4 v0 = msg4[s0 * 4 + fl];
        uint4 v1 = msg4[s1 * 4 + fl];
        uint4 v2 = msg4[s2 * 4 + fl];
        uint4 v3 = msg4[s3 * 4 + fl];
        uint4 v4 = msg4[s4 * 4 + fl];
        uint4 v5 = msg4[s5 * 4 + fl];
        uint4 v6 = msg4[s6 * 4 + fl];
        uint4 v7 = msg4[s7 * 4 + fl];
        acc16(v0, a); acc16(v1, a); acc16(v2, a); acc16(v3, a);
        acc16(v4, a); acc16(v5, a); acc16(v6, a); acc16(v7, a);
    }
    for (; e < end; e++) {
        int s = ssrc[e];
        uint4 v = msg4[s * 4 + fl];
        acc16(v, a);
    }
    if (act) {
        uint4 ta = tl4[n * 6 + fl * 2];
        uint4 tb = tl4[n * 6 + fl * 2 + 1];
        float p[16];
        float2 f;
        f = h2tof2(ta.x); p[0] = f.x;  p[1] = f.y;
        f = h2tof2(ta.y); p[2] = f.x;  p[3] = f.y;
        f = h2tof2(ta.z); p[4] = f.x;  p[5] = f.y;
        f = h2tof2(ta.w); p[6] = f.x;  p[7] = f.y;
        f = h2tof2(tb.x); p[8] = f.x;  p[9] = f.y;
        f = h2tof2(tb.y); p[10] = f.x; p[11] = f.y;
        f = h2tof2(tb.z); p[12] = f.x; p[13] = f.y;
        f = h2tof2(tb.w); p[14] = f.x; p[15] = f.y;
        const float4* b4 = (const float4*)bias;
        float r[16];
        #pragma unroll
        for (int q = 0; q < 4; q++) {
            float4 bi = b4[fl * 4 + q];
            r[q * 4 + 0] = fmaxf(p[q * 4 + 0] + a[q * 4 + 0] + bi.x, 0.f);
            r[q * 4 + 1] = fmaxf(p[q * 4 + 1] + a[q * 4 + 1] + bi.y, 0.f);
            r[q * 4 + 2] = fmaxf(p[q * 4 + 2] + a[q * 4 + 2] + bi.z, 0.f);
            r[q * 4 + 3] = fmaxf(p[q * 4 + 3] + a[q * 4 + 3] + bi.w, 0.f);
        }
        __half2 h0 = __floats2half2_rn(r[0], r[1]);
        __half2 h1 = __floats2half2_rn(r[2], r[3]);
        __half2 h2 = __floats2half2_rn(r[4], r[5]);
        __half2 h3 = __floats2half2_rn(r[6], r[7]);
        __half2 h4 = __floats2half2_rn(r[8], r[9]);
        __half2 h5 = __floats2half2_rn(r[10], r[11]);
        __half2 h6 = __floats2half2_rn(r[12], r[13]);
        __half2 h7 = __floats2half2_rn(r[14], r[15]);
        uint4 o0, o1;
        o0.x = *reinterpret_cast<unsigned int*>(&h0);
        o0.y = *reinterpret_cast<unsigned int*>(&h1);
        o0.z = *reinterpret_cast<unsigned int*>(&h2);
        o0.w = *reinterpret_cast<unsigned int*>(&h3);
        o1.x = *reinterpret_cast<unsigned int*>(&h4);
        o1.y = *reinterpret_cast<unsigned int*>(&h5);
        o1.z = *reinterpret_cast<unsigned int*>(&h6);
        o1.w = *reinterpret_cast<unsigned int*>(&h7);
        out4[n * 6 + fl * 2] = o0;
        out4[n * 6 + fl * 2 + 1] = o1;
    }
}

// ---------------- chain1 (MFMA): v=u@c1W2+b2; g=bn1(relu(v)); t3=g@c2W1 (fp16); t4=relu(g)@c2W1 (fp8 rows) ----------------
// u is fp16 [N][48]; staged by bit-copy. t3 aliases u (staged before first sync; row-exclusive).

__global__ __launch_bounds__(256) void k_chain1(const __half* u,
                                                const float* __restrict__ W2,
                                                const float* __restrict__ b2,
                                                const float* __restrict__ bng,
                                                const float* __restrict__ bnb,
                                                const float* __restrict__ bnm,
                                                const float* __restrict__ bnv,
                                                const float* __restrict__ W1n,
                                                __half* t3,
                                                unsigned char* __restrict__ t4f8) {
    __shared__ _Float16 sU[64 * PADC];
    __shared__ _Float16 sG[64 * PADC];
    __shared__ _Float16 sW2t[DIM * PADC];
    __shared__ _Float16 sW1t[DIM * PADC];
    __shared__ float sb2[DIM], ssc[DIM], ssh[DIM];
    const int t = threadIdx.x;
    const int base = blockIdx.x * 64;
    const int wid = t >> 6, lane = t & 63;

    if (t < DIM) {
        sb2[t] = b2[t];
        float sc = bng[t] * rsqrtf(bnv[t] + BN_EPS);
        ssc[t] = sc;
        ssh[t] = bnb[t] - bnm[t] * sc;
    }
    for (int idx = t; idx < DIM * 24; idx += 256) {
        int c = idx / 24, kk = (idx - c * 24) * 2;
        sW2t[c * PADC + kk]     = (_Float16)W2[kk * DIM + c];
        sW2t[c * PADC + kk + 1] = (_Float16)W2[(kk + 1) * DIM + c];
        sW1t[c * PADC + kk]     = (_Float16)W1n[kk * DIM + c];
        sW1t[c * PADC + kk + 1] = (_Float16)W1n[(kk + 1) * DIM + c];
    }
    for (int idx = t; idx < DIM * 16; idx += 256) {
        int c = idx >> 4, j = idx & 15;
        sW2t[c * PADC + 48 + j] = (_Float16)0;
        sW1t[c * PADC + 48 + j] = (_Float16)0;
    }
    for (int idx = t; idx < 64 * 16; idx += 256) {
        int r = idx >> 4, j = idx & 15;
        sU[r * PADC + 48 + j] = (_Float16)0;
        sG[r * PADC + 48 + j] = (_Float16)0;
    }
    for (int idx = t; idx < 64 * 12; idx += 256) {
        int row = idx / 12, kk = idx - row * 12;
        uint2 v = make_uint2(0u, 0u);
        if (base + row < N_NODES) v = ((const uint2*)u)[(base + row) * 12 + kk];
        *(uint2*)&sU[row * PADC + kk * 4] = v;
    }
    __syncthreads();

    const int r16 = wid * 16;
    const int lrow = lane & 15;
    const int lk = (lane >> 4) * 8;
    const int orow = r16 + (lane >> 4) * 4;
    const int ocol = lane & 15;

    f32x4 av[3];
    #pragma unroll
    for (int c = 0; c < 3; c++) av[c] = (f32x4){0.f, 0.f, 0.f, 0.f};
    #pragma unroll
    for (int ks = 0; ks < 2; ks++) {
        f16x8 a = *(const f16x8*)&sU[(r16 + lrow) * PADC + ks * 32 + lk];
        #pragma unroll
        for (int c = 0; c < 3; c++) {
            f16x8 b = *(const f16x8*)&sW2t[(c * 16 + lrow) * PADC + ks * 32 + lk];
            av[c] = __builtin_amdgcn_mfma_f32_16x16x32_f16(a, b, av[c], 0, 0, 0);
        }
    }
    #pragma unroll
    for (int c = 0; c < 3; c++) {
        int col = c * 16 + ocol;
        float bb = sb2[col], sc = ssc[col], sh = ssh[col];
        #pragma unroll
        for (int q = 0; q < 4; q++) {
            float rl = fmaxf(av[c][q] + bb, 0.f);
            sG[(orow + q) * PADC + col] = (_Float16)(rl * sc + sh);
        }
    }
    __syncthreads();

    f32x4 a3[3], a4[3];
    #pragma unroll
    for (int c = 0; c < 3; c++) {
        a3[c] = (f32x4){0.f, 0.f, 0.f, 0.f};
        a4[c] = (f32x4){0.f, 0.f, 0.f, 0.f};
    }
    #pragma unroll
    for (int ks = 0; ks < 2; ks++) {
        f16x8 a = *(const f16x8*)&sG[(r16 + lrow) * PADC + ks * 32 + lk];
        f16x8 ra;
        #pragma unroll
        for (int j = 0; j < 8; j++)
            ra[j] = a[j] > (_Float16)0 ? a[j] : (_Float16)0;
        #pragma unroll
        for (int c = 0; c < 3; c++) {
            f16x8 b = *(const f16x8*)&sW1t[(c * 16 + lrow) * PADC + ks * 32 + lk];
            a3[c] = __builtin_amdgcn_mfma_f32_16x16x32_f16(a,  b, a3[c], 0, 0, 0);
            a4[c] = __builtin_amdgcn_mfma_f32_16x16x32_f16(ra, b, a4[c], 0, 0, 0);
        }
    }
    #pragma unroll
    for (int q = 0; q < 4; q++) {
        int gr = base + orow + q;
        if (gr < N_NODES) {
            #pragma unroll
            for (int c = 0; c < 3; c++) {
                t3[gr * DIM + c * 16 + ocol] = __float2half(a3[c][q]);
                t4f8[(size_t)gr * MB8 + c * 16 + ocol] = f32tof8(a4[c][q]);
            }
        }
    }
}

// ---------------- chain2 (MFMA): v2=u2@c2W2+b2; g2=bn2(relu); z=relu(g2@fc1+b); out=z@fc2+b ----------------

__global__ __launch_bounds__(256) void k_chain2(const __half* __restrict__ u2,
                                                const float* __restrict__ W2,
                                                const float* __restrict__ b2,
                                                const float* __restrict__ bng,
                                                const float* __restrict__ bnb,
                                                const float* __restrict__ bnm,
                                                const float* __restrict__ bnv,
                                                const float* __restrict__ fc1W,
                                                const float* __restrict__ fc1b,
                                                const float* __restrict__ fc2W,
                                                const float* __restrict__ fc2b,
                                                float* __restrict__ out) {
    __shared__ _Float16 sA[64 * PADC];
    __shared__ _Float16 sG[64 * PADC];
    __shared__ _Float16 sWa[DIM * PADC];
    __shared__ _Float16 sWb[DIM * PADC];
    __shared__ _Float16 sWc[32 * PADC];
    __shared__ float sb2[DIM], ssc[DIM], ssh[DIM], sfb1[DIM], sfb2[N_CLASS];
    const int t = threadIdx.x;
    const int base = blockIdx.x * 64;
    const int wid = t >> 6, lane = t & 63;

    if (t < DIM) {
        sb2[t] = b2[t];
        float sc = bng[t] * rsqrtf(bnv[t] + BN_EPS);
        ssc[t] = sc;
        ssh[t] = bnb[t] - bnm[t] * sc;
        sfb1[t] = fc1b[t];
    }
    if (t >= 64 && t < 64 + N_CLASS) sfb2[t - 64] = fc2b[t - 64];

    for (int idx = t; idx < DIM * 24; idx += 256) {
        int c = idx / 24, kk = (idx - c * 24) * 2;
        sWa[c * PADC + kk]     = (_Float16)W2[kk * DIM + c];
        sWa[c * PADC + kk + 1] = (_Float16)W2[(kk + 1) * DIM + c];
        sWb[c * PADC + kk]     = (_Float16)fc1W[kk * DIM + c];
        sWb[c * PADC + kk + 1] = (_Float16)fc1W[(kk + 1) * DIM + c];
    }
    for (int idx = t; idx < DIM * 16; idx += 256) {
        int c = idx >> 4, j = idx & 15;
        sWa[c * PADC + 48 + j] = (_Float16)0;
        sWb[c * PADC + 48 + j] = (_Float16)0;
    }
    for (int idx = t; idx < N_CLASS * DIM; idx += 256) {
        int c = idx / DIM, k = idx - c * DIM;
        sWc[c * PADC + k] = (_Float16)fc2W[k * N_CLASS + c];
    }
    for (int idx = t; idx < 32 * 16; idx += 256) {
        int c = idx >> 4, j = idx & 15;
        sWc[c * PADC + 48 + j] = (_Float16)0;
    }
    for (int idx = t; idx < 14 * 48; idx += 256) {
        int c = 18 + idx / 48, k = idx - (idx / 48) * 48;
        sWc[c * PADC + k] = (_Float16)0;
    }
    for (int idx = t; idx < 64 * 16; idx += 256) {
        int r = idx >> 4, j = idx & 15;
        sA[r * PADC + 48 + j] = (_Float16)0;
        sG[r * PADC + 48 + j] = (_Float16)0;
    }
    for (int idx = t; idx < 64 * 12; idx += 256) {
        int row = idx / 12, kk = idx - row * 12;
        uint2 v = make_uint2(0u, 0u);
        if (base + row < N_NODES) v = ((const uint2*)u2)[(base + row) * 12 + kk];
        *(uint2*)&sA[row * PADC + kk * 4] = v;
    }
    __syncthreads();

    const int r16 = wid * 16;
    const int lrow = lane & 15;
    const int lk = (lane >> 4) * 8;
    const int orow = r16 + (lane >> 4) * 4;
    const int ocol = lane & 15;

    {
        f32x4 av[3];
        #pragma unroll
        for (int c = 0; c < 3; c++) av[c] = (f32x4){0.f, 0.f, 0.f, 0.f};
        #pragma unroll
        for (int ks = 0; ks < 2; ks++) {
            f16x8 a = *(const f16x8*)&sA[(r16 + lrow) * PADC + ks * 32 + lk];
            #pragma unroll
            for (int c = 0; c < 3; c++) {
                f16x8 b = *(const f16x8*)&sWa[(c * 16 + lrow) * PADC + ks * 32 + lk];
                av[c] = __builtin_amdgcn_mfma_f32_16x16x32_f16(a, b, av[c], 0, 0, 0);
            }
        }
        #pragma unroll
        for (int c = 0; c < 3; c++) {
            int col = c * 16 + ocol;
            float bb = sb2[col], sc = ssc[col], sh = ssh[col];
            #pragma unroll
            for (int q = 0; q < 4; q++) {
                float rl = fmaxf(av[c][q] + bb, 0.f);
                sG[(orow + q) * PADC + col] = (_Float16)(rl * sc + sh);
            }
        }
    }
    __syncthreads();

    {
        f32x4 az[3];
        #pragma unroll
        for (int c = 0; c < 3; c++) az[c] = (f32x4){0.f, 0.f, 0.f, 0.f};
        #pragma unroll
        for (int ks = 0; ks < 2; ks++) {
            f16x8 a = *(const f16x8*)&sG[(r16 + lrow) * PADC + ks * 32 + lk];
            #pragma unroll
            for (int c = 0; c < 3; c++) {
                f16x8 b = *(const f16x8*)&sWb[(c * 16 + lrow) * PADC + ks * 32 + lk];
                az[c] = __builtin_amdgcn_mfma_f32_16x16x32_f16(a, b, az[c], 0, 0, 0);
            }
        }
        __syncthreads();
        #pragma unroll
        for (int c = 0; c < 3; c++) {
            int col = c * 16 + ocol;
            float bb = sfb1[col];
            #pragma unroll
            for (int q = 0; q < 4; q++)
                sA[(orow + q) * PADC + col] = (_Float16)fmaxf(az[c][q] + bb, 0.f);
        }
    }
    __syncthreads();

    {
        f32x4 ao[2];
        #pragma unroll
        for (int c = 0; c < 2; c++) ao[c] = (f32x4){0.f, 0.f, 0.f, 0.f};
        #pragma unroll
        for (int ks = 0; ks < 2; ks++) {
            f16x8 a = *(const f16x8*)&sA[(r16 + lrow) * PADC + ks * 32 + lk];
            #pragma unroll
            for (int c = 0; c < 2; c++) {
                f16x8 b = *(const f16x8*)&sWc[(c * 16 + lrow) * PADC + ks * 32 + lk];
                ao[c] = __builtin_amdgcn_mfma_f32_16x16x32_f16(a, b, ao[c], 0, 0, 0);
            }
        }
        #pragma unroll
        for (int q = 0; q < 4; q++) {
            int gr = base + orow + q;
            if (gr < N_NODES) {
                #pragma unroll
                for (int c = 0; c < 2; c++) {
                    int col = c * 16 + ocol;
                    if (col < N_CLASS)
                        out[gr * N_CLASS + col] = ao[c][q] + sfb2[col];
                }
            }
        }
    }
}

// ---------------- launch ----------------

extern "C" void kernel_launch(void* const* d_in, const int* in_sizes, int n_in,
                              void* d_out, int out_size, void* d_ws, size_t ws_size,
                              hipStream_t stream) {
    const float* x     = (const float*)d_in[0];
    const int*   ei    = (const int*)d_in[1];
    const float* c1_W1 = (const float*)d_in[2];
    const float* c1_b1 = (const float*)d_in[3];
    const float* c1_W2 = (const float*)d_in[4];
    const float* c1_b2 = (const float*)d_in[5];
    const float* c2_W1 = (const float*)d_in[6];
    const float* c2_b1 = (const float*)d_in[7];
    const float* c2_W2 = (const float*)d_in[8];
    const float* c2_b2 = (const float*)d_in[9];
    const float* bn1_g = (const float*)d_in[10];
    const float* bn1_b = (const float*)d_in[11];
    const float* bn1_m = (const float*)d_in[12];
    const float* bn1_v = (const float*)d_in[13];
    const float* bn2_g = (const float*)d_in[14];
    const float* bn2_b = (const float*)d_in[15];
    const float* bn2_m = (const float*)d_in[16];
    const float* bn2_v = (const float*)d_in[17];
    const float* fc1_W = (const float*)d_in[18];
    const float* fc1_b = (const float*)d_in[19];
    const float* fc2_W = (const float*)d_in[20];
    const float* fc2_b = (const float*)d_in[21];
    float* out = (float*)d_out;

    char* ws = (char*)d_ws;
    size_t o = 0;
    auto take = [&](size_t bytes) {
        void* p = ws + o;
        o = (o + bytes + 255) & ~(size_t)255;
        return p;
    };
    unsigned int* pairs = (unsigned int*)take((size_t)NBUCK * BCAP * 4);   // 14.4 MB
    int*  sorted_src    = (int*)take((size_t)NBUCK * BCAP * 4);            // 14.4 MB
    int*  row_beg       = (int*)take((size_t)N_NODES * 4);
    int*  row_end       = (int*)take((size_t)N_NODES * 4);
    int*  bcursor       = (int*)take((size_t)NBUCK * 4);
    __half* t1h         = (__half*)take((size_t)N_NODES * DIM * 2);        // t1 / u / t3 / u2 (fp16)
    unsigned char* m8   = (unsigned char*)take((size_t)N_NODES * MB8);     // fp8 messages (64B rows)
    (void)ws_size; (void)in_sizes; (void)n_in; (void)out_size;

    const int NB84 = (N_NODES + 83) / 84;    // 1191

    hipMemsetAsync(bcursor, 0, (size_t)NBUCK * 4, stream);
    k_bin<<<NBLK_E, 256, 0, stream>>>(ei, bcursor, pairs);
    k_sortg1<<<NBUCK + NB64, 256, 0, stream>>>(pairs, bcursor, row_beg, row_end, sorted_src,
                                               x, c1_W1, t1h, m8);
    k_aggr<<<NB84, 256, 0, stream>>>((const uint4*)t1h, (const uint4*)m8,
                                     row_beg, row_end, sorted_src, c1_b1, (uint4*)t1h);
    k_chain1<<<NB64, 256, 0, stream>>>(t1h, c1_W2, c1_b2, bn1_g, bn1_b, bn1_m, bn1_v,
                                       c2_W1, t1h, m8);
    k_aggr<<<NB84, 256, 0, stream>>>((const uint4*)t1h, (const uint4*)m8,
                                     row_beg, row_end, sorted_src, c2_b1, (uint4*)t1h);
    k_chain2<<<NB64, 256, 0, stream>>>(t1h, c2_W2, c2_b2, bn2_g, bn2_b, bn2_m, bn2_v,
                                       fc1_W, fc1_b, fc2_W, fc2_b, out);
}

// Round 22
// 220.112 us; speedup vs baseline: 1.0737x; 1.0737x over previous
//
#include <hip/hip_runtime.h>
#include <hip/hip_fp16.h>
#include <hip/hip_fp8.h>

#define N_NODES 100000
#define N_EDGES 3200000
#define N_FEAT  128
#define DIM     48
#define N_CLASS 18
#define BN_EPS  1e-5f

#define PADW 136   // f16 MFMA K=128 tile row stride
#define PADC 72    // f16 MFMA K=64 tile row stride
#define MB8  64    // fp8 message-row stride in BYTES (48B payload, 64B aligned)

#define BSH    8                                   // bucket = dst >> 8 (256 nodes)
#define BROWS  256
#define NBUCK  ((N_NODES + BROWS - 1) / BROWS)     // 391
#define BCAP   9216
#define EPB    4096
#define NBLK_E ((N_EDGES + EPB - 1) / EPB)         // 782
#define EPT    36                                  // edges per thread reg-cache (36*256 = BCAP)

#define NB64   ((N_NODES + 63) / 64)               // 1563

typedef __attribute__((ext_vector_type(8))) _Float16 f16x8;
typedef __attribute__((ext_vector_type(4))) float f32x4;

// packed edge: (src << 8) | (dst & 255)  — src < 2^17, fits 25 bits

__device__ __forceinline__ unsigned char f32tof8(float v) {
    __hip_fp8_e4m3 h(v);
    return (unsigned char)h.__x;
}
__device__ __forceinline__ float f8tof32(unsigned char b) {
    __hip_fp8_e4m3 h; h.__x = (__hip_fp8_storage_t)b;
    return (float)h;
}

// ---------------- binning: direct scatter into slack bucket windows ----------------

__global__ __launch_bounds__(256) void k_bin(const int* __restrict__ ei,
                                             int* __restrict__ bcursor,
                                             unsigned int* __restrict__ pairs) {
    __shared__ int h[NBUCK];
    __shared__ int pos[NBUCK];
    const int t = threadIdx.x;
    const int bs = blockIdx.x * EPB;
    const int ce = min(EPB, N_EDGES - bs);

    int sv[16], dv[16];
    #pragma unroll
    for (int i = 0; i < 16; i++) {
        int e = t + i * 256;
        if (e < ce) { sv[i] = ei[bs + e]; dv[i] = ei[N_EDGES + bs + e]; }
        else { sv[i] = 0; dv[i] = -1; }
    }
    for (int i = t; i < NBUCK; i += 256) h[i] = 0;
    __syncthreads();
    #pragma unroll
    for (int i = 0; i < 16; i++)
        if (dv[i] >= 0) atomicAdd(&h[dv[i] >> BSH], 1);
    __syncthreads();

    for (int b = t; b < NBUCK; b += 256) {
        int cnt = h[b];
        if (cnt > 0) {
            int g = atomicAdd(&bcursor[b], cnt);
            h[b] = b * BCAP + g;
        }
        pos[b] = 0;
    }
    __syncthreads();

    #pragma unroll
    for (int i = 0; i < 16; i++) {
        if (dv[i] >= 0) {
            int b = dv[i] >> BSH;
            int p = atomicAdd(&pos[b], 1);
            pairs[h[b] + p] = ((unsigned int)sv[i] << 8) | (unsigned int)(dv[i] & (BROWS - 1));
        }
    }
}

// ---------------- fused: per-bucket counting sort (blocks 0..390) + conv1-front MFMA ----------------
// Sort: ONE global read of pairs (reg-cached, EPT=36/thread), LDS-staged scatter,
// linear coalesced copy-out.

__global__ __launch_bounds__(256) void k_sortg1(const unsigned int* __restrict__ pairs,
                                                const int* __restrict__ bcursor,
                                                int* __restrict__ row_beg,
                                                int* __restrict__ row_end,
                                                int* __restrict__ sorted_src,
                                                const float* __restrict__ x,
                                                const float* __restrict__ W1,
                                                __half* __restrict__ t1,
                                                unsigned char* __restrict__ t2f8) {
    __shared__ __align__(16) char smem[47104];
    const int t = threadIdx.x;

    if (blockIdx.x < NBUCK) {
        int* histw = (int*)smem;                  // 4*BROWS = 4096 B
        int* woff  = (int*)(smem + 4096);         // 4096 B
        int* scn   = (int*)(smem + 8192);         // 1024 B
        int* beg   = (int*)(smem + 9216);         // 1024 B
        int* stage = (int*)(smem + 10240);        // BCAP*4 = 36864 B
        const int wid = t >> 6;
        const int b = blockIdx.x;
        const int nbase = b << BSH;
        const int start_w = b * BCAP;
        const int cnt = bcursor[b];

        unsigned int pr[EPT];
        #pragma unroll
        for (int i = 0; i < EPT; i++) {
            int e = t + i * 256;
            pr[i] = (e < cnt) ? pairs[start_w + e] : 0xFFFFFFFFu;
        }
        for (int i = t; i < 4 * BROWS; i += 256) histw[i] = 0;
        __syncthreads();
        #pragma unroll
        for (int i = 0; i < EPT; i++)
            if (pr[i] != 0xFFFFFFFFu)
                atomicAdd(&histw[wid * BROWS + (int)(pr[i] & (BROWS - 1))], 1);
        __syncthreads();

        int run = 0;
        #pragma unroll
        for (int w = 0; w < 4; w++) {
            woff[w * BROWS + t] = run;
            run += histw[w * BROWS + t];
        }
        int tot = run;
        scn[t] = tot;
        __syncthreads();
        for (int off = 1; off < BROWS; off <<= 1) {
            int v = (t >= off) ? scn[t - off] : 0;
            __syncthreads();
            scn[t] += v;
            __syncthreads();
        }
        int rb = scn[t] - tot;
        beg[t] = rb;
        {
            int n = nbase + t;
            if (n < N_NODES) {
                row_beg[n] = start_w + rb;
                row_end[n] = start_w + rb + tot;
            }
        }
        __syncthreads();
        #pragma unroll
        for (int w = 0; w < 4; w++)
            histw[w * BROWS + t] = beg[t] + woff[w * BROWS + t];
        __syncthreads();
        #pragma unroll
        for (int i = 0; i < EPT; i++) {
            if (pr[i] != 0xFFFFFFFFu) {
                int node = (int)(pr[i] & (BROWS - 1));
                int idx = atomicAdd(&histw[wid * BROWS + node], 1);
                stage[idx] = (int)(pr[i] >> 8);
            }
        }
        __syncthreads();
        for (int i = t; i < cnt; i += 256)
            sorted_src[start_w + i] = stage[i];
    } else {
        // ---- g1 body: t1 = x@W1 (fp16), msgs = relu(x)@W1 (fp8) ----
        _Float16* sX = (_Float16*)smem;                        // 64*PADW*2 = 17408 B
        _Float16* sW = (_Float16*)(smem + 64 * PADW * 2);      // 48*PADW*2 = 13056 B
        const int base = (blockIdx.x - NBUCK) * 64;
        const int wid = t >> 6, lane = t & 63;

        for (int idx = t; idx < DIM * (N_FEAT / 2); idx += 256) {
            int c = idx >> 6;
            int kk = (idx & 63) * 2;
            *(__half2*)&sW[c * PADW + kk] =
                __floats2half2_rn(W1[kk * DIM + c], W1[(kk + 1) * DIM + c]);
        }
        #pragma unroll
        for (int i = 0; i < 8; i++) {
            int idx = t + i * 256;
            int row = idx >> 5, kq = idx & 31;
            float4 v = make_float4(0.f, 0.f, 0.f, 0.f);
            if (base + row < N_NODES) v = ((const float4*)x)[(base + row) * 32 + kq];
            *(__half2*)&sX[row * PADW + kq * 4]     = __floats2half2_rn(v.x, v.y);
            *(__half2*)&sX[row * PADW + kq * 4 + 2] = __floats2half2_rn(v.z, v.w);
        }
        __syncthreads();

        const int r16 = wid * 16;
        const int lrow = lane & 15;
        const int lk = (lane >> 4) * 8;

        f32x4 acc1[3], acc2[3];
        #pragma unroll
        for (int c = 0; c < 3; c++) {
            acc1[c] = (f32x4){0.f, 0.f, 0.f, 0.f};
            acc2[c] = (f32x4){0.f, 0.f, 0.f, 0.f};
        }

        #pragma unroll
        for (int ks = 0; ks < 4; ks++) {
            f16x8 a = *(const f16x8*)&sX[(r16 + lrow) * PADW + ks * 32 + lk];
            f16x8 ra;
            #pragma unroll
            for (int j = 0; j < 8; j++)
                ra[j] = a[j] > (_Float16)0 ? a[j] : (_Float16)0;
            #pragma unroll
            for (int c = 0; c < 3; c++) {
                f16x8 b = *(const f16x8*)&sW[(c * 16 + lrow) * PADW + ks * 32 + lk];
                acc1[c] = __builtin_amdgcn_mfma_f32_16x16x32_f16(a,  b, acc1[c], 0, 0, 0);
                acc2[c] = __builtin_amdgcn_mfma_f32_16x16x32_f16(ra, b, acc2[c], 0, 0, 0);
            }
        }

        const int orow = r16 + (lane >> 4) * 4;
        const int ocol = lane & 15;
        #pragma unroll
        for (int q = 0; q < 4; q++) {
            int gr = base + orow + q;
            if (gr < N_NODES) {
                #pragma unroll
                for (int c = 0; c < 3; c++) {
                    t1[gr * DIM + c * 16 + ocol] = __float2half(acc1[c][q]);
                    t2f8[(size_t)gr * MB8 + c * 16 + ocol] = f32tof8(acc2[c][q]);
                }
            }
        }
    }
}

// ---------------- aggregation: u = relu(tlin + segsum(msg_fp8) + bias) ----------------
// 10 nodes/wave (6 lanes/node, 8B = 8 fp8 feats per lane). msg rows 64B = 1 line.
// out aliases tlin (read-before-write, same thread, row-exclusive).

__device__ inline float2 h2tof2(unsigned int u) {
    __half2 h = *reinterpret_cast<__half2*>(&u);
    return __half22float2(h);
}

__device__ __forceinline__ void accf8(uint2 v,
    float& a0, float& a1, float& a2, float& a3,
    float& a4, float& a5, float& a6, float& a7) {
    a0 += f8tof32((unsigned char)(v.x));
    a1 += f8tof32((unsigned char)(v.x >> 8));
    a2 += f8tof32((unsigned char)(v.x >> 16));
    a3 += f8tof32((unsigned char)(v.x >> 24));
    a4 += f8tof32((unsigned char)(v.y));
    a5 += f8tof32((unsigned char)(v.y >> 8));
    a6 += f8tof32((unsigned char)(v.y >> 16));
    a7 += f8tof32((unsigned char)(v.y >> 24));
}

__global__ __launch_bounds__(256) void k_aggr(const uint2* tl8,                  // fp16 [N][12] chunks
                                              const uint2* __restrict__ msg8,    // fp8 [N][8] 8B chunks
                                              const int* __restrict__ row_beg,
                                              const int* __restrict__ row_end,
                                              const int* __restrict__ ssrc,
                                              const float* __restrict__ bias,
                                              uint2* out8) {
    const int t = threadIdx.x;
    const int wid = t >> 6, lane = t & 63;
    const int sub = lane / 6;           // 0..10 (10 = idle lanes 60..63)
    const int fl  = lane - sub * 6;     // 0..5 -> feats fl*8 .. fl*8+7
    int n = blockIdx.x * 40 + wid * 10 + sub;
    const bool act = (sub < 10) && (n < N_NODES);
    int start = 0, end = 0;
    if (act) { start = row_beg[n]; end = row_end[n]; }

    float a0 = 0.f, a1 = 0.f, a2 = 0.f, a3 = 0.f;
    float a4 = 0.f, a5 = 0.f, a6 = 0.f, a7 = 0.f;
    int e = start;
    for (; e + 8 <= end; e += 8) {
        int s0 = ssrc[e], s1 = ssrc[e + 1], s2 = ssrc[e + 2], s3 = ssrc[e + 3];
        int s4 = ssrc[e + 4], s5 = ssrc[e + 5], s6 = ssrc[e + 6], s7 = ssrc[e + 7];
        uint2 v0 = msg8[s0 * 8 + fl];
        uint2 v1 = msg8[s1 * 8 + fl];
        uint2 v2 = msg8[s2 * 8 + fl];
        uint2 v3 = msg8[s3 * 8 + fl];
        uint2 v4 = msg8[s4 * 8 + fl];
        uint2 v5 = msg8[s5 * 8 + fl];
        uint2 v6 = msg8[s6 * 8 + fl];
        uint2 v7 = msg8[s7 * 8 + fl];
        accf8(v0, a0, a1, a2, a3, a4, a5, a6, a7);
        accf8(v1, a0, a1, a2, a3, a4, a5, a6, a7);
        accf8(v2, a0, a1, a2, a3, a4, a5, a6, a7);
        accf8(v3, a0, a1, a2, a3, a4, a5, a6, a7);
        accf8(v4, a0, a1, a2, a3, a4, a5, a6, a7);
        accf8(v5, a0, a1, a2, a3, a4, a5, a6, a7);
        accf8(v6, a0, a1, a2, a3, a4, a5, a6, a7);
        accf8(v7, a0, a1, a2, a3, a4, a5, a6, a7);
    }
    for (; e < end; e++) {
        int s = ssrc[e];
        uint2 v = msg8[s * 8 + fl];
        accf8(v, a0, a1, a2, a3, a4, a5, a6, a7);
    }
    if (act) {
        uint2 ta = tl8[n * 12 + fl * 2];
        uint2 tb = tl8[n * 12 + fl * 2 + 1];
        float2 p0 = h2tof2(ta.x), p1 = h2tof2(ta.y);
        float2 p2 = h2tof2(tb.x), p3 = h2tof2(tb.y);
        const float4* b4 = (const float4*)bias;
        float4 bi0 = b4[fl * 2], bi1 = b4[fl * 2 + 1];
        float r0 = fmaxf(p0.x + a0 + bi0.x, 0.f);
        float r1 = fmaxf(p0.y + a1 + bi0.y, 0.f);
        float r2 = fmaxf(p1.x + a2 + bi0.z, 0.f);
        float r3 = fmaxf(p1.y + a3 + bi0.w, 0.f);
        float r4 = fmaxf(p2.x + a4 + bi1.x, 0.f);
        float r5 = fmaxf(p2.y + a5 + bi1.y, 0.f);
        float r6 = fmaxf(p3.x + a6 + bi1.z, 0.f);
        float r7 = fmaxf(p3.y + a7 + bi1.w, 0.f);
        __half2 h0 = __floats2half2_rn(r0, r1);
        __half2 h1 = __floats2half2_rn(r2, r3);
        __half2 h2 = __floats2half2_rn(r4, r5);
        __half2 h3 = __floats2half2_rn(r6, r7);
        uint2 o0, o1;
        o0.x = *reinterpret_cast<unsigned int*>(&h0);
        o0.y = *reinterpret_cast<unsigned int*>(&h1);
        o1.x = *reinterpret_cast<unsigned int*>(&h2);
        o1.y = *reinterpret_cast<unsigned int*>(&h3);
        out8[n * 12 + fl * 2] = o0;
        out8[n * 12 + fl * 2 + 1] = o1;
    }
}

// ---------------- chain1 (MFMA): v=u@c1W2+b2; g=bn1(relu(v)); t3=g@c2W1 (fp16); t4=relu(g)@c2W1 (fp8 rows) ----------------
// u is fp16 [N][48]; staged by bit-copy. t3 aliases u (staged before first sync; row-exclusive).

__global__ __launch_bounds__(256) void k_chain1(const __half* u,
                                                const float* __restrict__ W2,
                                                const float* __restrict__ b2,
                                                const float* __restrict__ bng,
                                                const float* __restrict__ bnb,
                                                const float* __restrict__ bnm,
                                                const float* __restrict__ bnv,
                                                const float* __restrict__ W1n,
                                                __half* t3,
                                                unsigned char* __restrict__ t4f8) {
    __shared__ _Float16 sU[64 * PADC];
    __shared__ _Float16 sG[64 * PADC];
    __shared__ _Float16 sW2t[DIM * PADC];
    __shared__ _Float16 sW1t[DIM * PADC];
    __shared__ float sb2[DIM], ssc[DIM], ssh[DIM];
    const int t = threadIdx.x;
    const int base = blockIdx.x * 64;
    const int wid = t >> 6, lane = t & 63;

    if (t < DIM) {
        sb2[t] = b2[t];
        float sc = bng[t] * rsqrtf(bnv[t] + BN_EPS);
        ssc[t] = sc;
        ssh[t] = bnb[t] - bnm[t] * sc;
    }
    for (int idx = t; idx < DIM * 24; idx += 256) {
        int c = idx / 24, kk = (idx - c * 24) * 2;
        sW2t[c * PADC + kk]     = (_Float16)W2[kk * DIM + c];
        sW2t[c * PADC + kk + 1] = (_Float16)W2[(kk + 1) * DIM + c];
        sW1t[c * PADC + kk]     = (_Float16)W1n[kk * DIM + c];
        sW1t[c * PADC + kk + 1] = (_Float16)W1n[(kk + 1) * DIM + c];
    }
    for (int idx = t; idx < DIM * 16; idx += 256) {
        int c = idx >> 4, j = idx & 15;
        sW2t[c * PADC + 48 + j] = (_Float16)0;
        sW1t[c * PADC + 48 + j] = (_Float16)0;
    }
    for (int idx = t; idx < 64 * 16; idx += 256) {
        int r = idx >> 4, j = idx & 15;
        sU[r * PADC + 48 + j] = (_Float16)0;
        sG[r * PADC + 48 + j] = (_Float16)0;
    }
    for (int idx = t; idx < 64 * 12; idx += 256) {
        int row = idx / 12, kk = idx - row * 12;
        uint2 v = make_uint2(0u, 0u);
        if (base + row < N_NODES) v = ((const uint2*)u)[(base + row) * 12 + kk];
        *(uint2*)&sU[row * PADC + kk * 4] = v;
    }
    __syncthreads();

    const int r16 = wid * 16;
    const int lrow = lane & 15;
    const int lk = (lane >> 4) * 8;
    const int orow = r16 + (lane >> 4) * 4;
    const int ocol = lane & 15;

    f32x4 av[3];
    #pragma unroll
    for (int c = 0; c < 3; c++) av[c] = (f32x4){0.f, 0.f, 0.f, 0.f};
    #pragma unroll
    for (int ks = 0; ks < 2; ks++) {
        f16x8 a = *(const f16x8*)&sU[(r16 + lrow) * PADC + ks * 32 + lk];
        #pragma unroll
        for (int c = 0; c < 3; c++) {
            f16x8 b = *(const f16x8*)&sW2t[(c * 16 + lrow) * PADC + ks * 32 + lk];
            av[c] = __builtin_amdgcn_mfma_f32_16x16x32_f16(a, b, av[c], 0, 0, 0);
        }
    }
    #pragma unroll
    for (int c = 0; c < 3; c++) {
        int col = c * 16 + ocol;
        float bb = sb2[col], sc = ssc[col], sh = ssh[col];
        #pragma unroll
        for (int q = 0; q < 4; q++) {
            float rl = fmaxf(av[c][q] + bb, 0.f);
            sG[(orow + q) * PADC + col] = (_Float16)(rl * sc + sh);
        }
    }
    __syncthreads();

    f32x4 a3[3], a4[3];
    #pragma unroll
    for (int c = 0; c < 3; c++) {
        a3[c] = (f32x4){0.f, 0.f, 0.f, 0.f};
        a4[c] = (f32x4){0.f, 0.f, 0.f, 0.f};
    }
    #pragma unroll
    for (int ks = 0; ks < 2; ks++) {
        f16x8 a = *(const f16x8*)&sG[(r16 + lrow) * PADC + ks * 32 + lk];
        f16x8 ra;
        #pragma unroll
        for (int j = 0; j < 8; j++)
            ra[j] = a[j] > (_Float16)0 ? a[j] : (_Float16)0;
        #pragma unroll
        for (int c = 0; c < 3; c++) {
            f16x8 b = *(const f16x8*)&sW1t[(c * 16 + lrow) * PADC + ks * 32 + lk];
            a3[c] = __builtin_amdgcn_mfma_f32_16x16x32_f16(a,  b, a3[c], 0, 0, 0);
            a4[c] = __builtin_amdgcn_mfma_f32_16x16x32_f16(ra, b, a4[c], 0, 0, 0);
        }
    }
    #pragma unroll
    for (int q = 0; q < 4; q++) {
        int gr = base + orow + q;
        if (gr < N_NODES) {
            #pragma unroll
            for (int c = 0; c < 3; c++) {
                t3[gr * DIM + c * 16 + ocol] = __float2half(a3[c][q]);
                t4f8[(size_t)gr * MB8 + c * 16 + ocol] = f32tof8(a4[c][q]);
            }
        }
    }
}

// ---------------- chain2 (MFMA): v2=u2@c2W2+b2; g2=bn2(relu); z=relu(g2@fc1+b); out=z@fc2+b ----------------

__global__ __launch_bounds__(256) void k_chain2(const __half* __restrict__ u2,
                                                const float* __restrict__ W2,
                                                const float* __restrict__ b2,
                                                const float* __restrict__ bng,
                                                const float* __restrict__ bnb,
                                                const float* __restrict__ bnm,
                                                const float* __restrict__ bnv,
                                                const float* __restrict__ fc1W,
                                                const float* __restrict__ fc1b,
                                                const float* __restrict__ fc2W,
                                                const float* __restrict__ fc2b,
                                                float* __restrict__ out) {
    __shared__ _Float16 sA[64 * PADC];
    __shared__ _Float16 sG[64 * PADC];
    __shared__ _Float16 sWa[DIM * PADC];
    __shared__ _Float16 sWb[DIM * PADC];
    __shared__ _Float16 sWc[32 * PADC];
    __shared__ float sb2[DIM], ssc[DIM], ssh[DIM], sfb1[DIM], sfb2[N_CLASS];
    const int t = threadIdx.x;
    const int base = blockIdx.x * 64;
    const int wid = t >> 6, lane = t & 63;

    if (t < DIM) {
        sb2[t] = b2[t];
        float sc = bng[t] * rsqrtf(bnv[t] + BN_EPS);
        ssc[t] = sc;
        ssh[t] = bnb[t] - bnm[t] * sc;
        sfb1[t] = fc1b[t];
    }
    if (t >= 64 && t < 64 + N_CLASS) sfb2[t - 64] = fc2b[t - 64];

    for (int idx = t; idx < DIM * 24; idx += 256) {
        int c = idx / 24, kk = (idx - c * 24) * 2;
        sWa[c * PADC + kk]     = (_Float16)W2[kk * DIM + c];
        sWa[c * PADC + kk + 1] = (_Float16)W2[(kk + 1) * DIM + c];
        sWb[c * PADC + kk]     = (_Float16)fc1W[kk * DIM + c];
        sWb[c * PADC + kk + 1] = (_Float16)fc1W[(kk + 1) * DIM + c];
    }
    for (int idx = t; idx < DIM * 16; idx += 256) {
        int c = idx >> 4, j = idx & 15;
        sWa[c * PADC + 48 + j] = (_Float16)0;
        sWb[c * PADC + 48 + j] = (_Float16)0;
    }
    for (int idx = t; idx < N_CLASS * DIM; idx += 256) {
        int c = idx / DIM, k = idx - c * DIM;
        sWc[c * PADC + k] = (_Float16)fc2W[k * N_CLASS + c];
    }
    for (int idx = t; idx < 32 * 16; idx += 256) {
        int c = idx >> 4, j = idx & 15;
        sWc[c * PADC + 48 + j] = (_Float16)0;
    }
    for (int idx = t; idx < 14 * 48; idx += 256) {
        int c = 18 + idx / 48, k = idx - (idx / 48) * 48;
        sWc[c * PADC + k] = (_Float16)0;
    }
    for (int idx = t; idx < 64 * 16; idx += 256) {
        int r = idx >> 4, j = idx & 15;
        sA[r * PADC + 48 + j] = (_Float16)0;
        sG[r * PADC + 48 + j] = (_Float16)0;
    }
    for (int idx = t; idx < 64 * 12; idx += 256) {
        int row = idx / 12, kk = idx - row * 12;
        uint2 v = make_uint2(0u, 0u);
        if (base + row < N_NODES) v = ((const uint2*)u2)[(base + row) * 12 + kk];
        *(uint2*)&sA[row * PADC + kk * 4] = v;
    }
    __syncthreads();

    const int r16 = wid * 16;
    const int lrow = lane & 15;
    const int lk = (lane >> 4) * 8;
    const int orow = r16 + (lane >> 4) * 4;
    const int ocol = lane & 15;

    {
        f32x4 av[3];
        #pragma unroll
        for (int c = 0; c < 3; c++) av[c] = (f32x4){0.f, 0.f, 0.f, 0.f};
        #pragma unroll
        for (int ks = 0; ks < 2; ks++) {
            f16x8 a = *(const f16x8*)&sA[(r16 + lrow) * PADC + ks * 32 + lk];
            #pragma unroll
            for (int c = 0; c < 3; c++) {
                f16x8 b = *(const f16x8*)&sWa[(c * 16 + lrow) * PADC + ks * 32 + lk];
                av[c] = __builtin_amdgcn_mfma_f32_16x16x32_f16(a, b, av[c], 0, 0, 0);
            }
        }
        #pragma unroll
        for (int c = 0; c < 3; c++) {
            int col = c * 16 + ocol;
            float bb = sb2[col], sc = ssc[col], sh = ssh[col];
            #pragma unroll
            for (int q = 0; q < 4; q++) {
                float rl = fmaxf(av[c][q] + bb, 0.f);
                sG[(orow + q) * PADC + col] = (_Float16)(rl * sc + sh);
            }
        }
    }
    __syncthreads();

    {
        f32x4 az[3];
        #pragma unroll
        for (int c = 0; c < 3; c++) az[c] = (f32x4){0.f, 0.f, 0.f, 0.f};
        #pragma unroll
        for (int ks = 0; ks < 2; ks++) {
            f16x8 a = *(const f16x8*)&sG[(r16 + lrow) * PADC + ks * 32 + lk];
            #pragma unroll
            for (int c = 0; c < 3; c++) {
                f16x8 b = *(const f16x8*)&sWb[(c * 16 + lrow) * PADC + ks * 32 + lk];
                az[c] = __builtin_amdgcn_mfma_f32_16x16x32_f16(a, b, az[c], 0, 0, 0);
            }
        }
        __syncthreads();
        #pragma unroll
        for (int c = 0; c < 3; c++) {
            int col = c * 16 + ocol;
            float bb = sfb1[col];
            #pragma unroll
            for (int q = 0; q < 4; q++)
                sA[(orow + q) * PADC + col] = (_Float16)fmaxf(az[c][q] + bb, 0.f);
        }
    }
    __syncthreads();

    {
        f32x4 ao[2];
        #pragma unroll
        for (int c = 0; c < 2; c++) ao[c] = (f32x4){0.f, 0.f, 0.f, 0.f};
        #pragma unroll
        for (int ks = 0; ks < 2; ks++) {
            f16x8 a = *(const f16x8*)&sA[(r16 + lrow) * PADC + ks * 32 + lk];
            #pragma unroll
            for (int c = 0; c < 2; c++) {
                f16x8 b = *(const f16x8*)&sWc[(c * 16 + lrow) * PADC + ks * 32 + lk];
                ao[c] = __builtin_amdgcn_mfma_f32_16x16x32_f16(a, b, ao[c], 0, 0, 0);
            }
        }
        #pragma unroll
        for (int q = 0; q < 4; q++) {
            int gr = base + orow + q;
            if (gr < N_NODES) {
                #pragma unroll
                for (int c = 0; c < 2; c++) {
                    int col = c * 16 + ocol;
                    if (col < N_CLASS)
                        out[gr * N_CLASS + col] = ao[c][q] + sfb2[col];
                }
            }
        }
    }
}

// ---------------- launch ----------------

extern "C" void kernel_launch(void* const* d_in, const int* in_sizes, int n_in,
                              void* d_out, int out_size, void* d_ws, size_t ws_size,
                              hipStream_t stream) {
    const float* x     = (const float*)d_in[0];
    const int*   ei    = (const int*)d_in[1];
    const float* c1_W1 = (const float*)d_in[2];
    const float* c1_b1 = (const float*)d_in[3];
    const float* c1_W2 = (const float*)d_in[4];
    const float* c1_b2 = (const float*)d_in[5];
    const float* c2_W1 = (const float*)d_in[6];
    const float* c2_b1 = (const float*)d_in[7];
    const float* c2_W2 = (const float*)d_in[8];
    const float* c2_b2 = (const float*)d_in[9];
    const float* bn1_g = (const float*)d_in[10];
    const float* bn1_b = (const float*)d_in[11];
    const float* bn1_m = (const float*)d_in[12];
    const float* bn1_v = (const float*)d_in[13];
    const float* bn2_g = (const float*)d_in[14];
    const float* bn2_b = (const float*)d_in[15];
    const float* bn2_m = (const float*)d_in[16];
    const float* bn2_v = (const float*)d_in[17];
    const float* fc1_W = (const float*)d_in[18];
    const float* fc1_b = (const float*)d_in[19];
    const float* fc2_W = (const float*)d_in[20];
    const float* fc2_b = (const float*)d_in[21];
    float* out = (float*)d_out;

    char* ws = (char*)d_ws;
    size_t o = 0;
    auto take = [&](size_t bytes) {
        void* p = ws + o;
        o = (o + bytes + 255) & ~(size_t)255;
        return p;
    };
    unsigned int* pairs = (unsigned int*)take((size_t)NBUCK * BCAP * 4);   // 14.4 MB
    int*  sorted_src    = (int*)take((size_t)NBUCK * BCAP * 4);            // 14.4 MB
    int*  row_beg       = (int*)take((size_t)N_NODES * 4);
    int*  row_end       = (int*)take((size_t)N_NODES * 4);
    int*  bcursor       = (int*)take((size_t)NBUCK * 4);
    __half* t1h         = (__half*)take((size_t)N_NODES * DIM * 2);        // t1 / u / t3 / u2 (fp16)
    unsigned char* m8   = (unsigned char*)take((size_t)N_NODES * MB8);     // fp8 messages (64B rows)
    (void)ws_size; (void)in_sizes; (void)n_in; (void)out_size;

    const int NB40 = (N_NODES + 39) / 40;    // 2500

    hipMemsetAsync(bcursor, 0, (size_t)NBUCK * 4, stream);
    k_bin<<<NBLK_E, 256, 0, stream>>>(ei, bcursor, pairs);
    k_sortg1<<<NBUCK + NB64, 256, 0, stream>>>(pairs, bcursor, row_beg, row_end, sorted_src,
                                               x, c1_W1, t1h, m8);
    k_aggr<<<NB40, 256, 0, stream>>>((const uint2*)t1h, (const uint2*)m8,
                                     row_beg, row_end, sorted_src, c1_b1, (uint2*)t1h);
    k_chain1<<<NB64, 256, 0, stream>>>(t1h, c1_W2, c1_b2, bn1_g, bn1_b, bn1_m, bn1_v,
                                       c2_W1, t1h, m8);
    k_aggr<<<NB40, 256, 0, stream>>>((const uint2*)t1h, (const uint2*)m8,
                                     row_beg, row_end, sorted_src, c2_b1, (uint2*)t1h);
    k_chain2<<<NB64, 256, 0, stream>>>(t1h, c2_W2, c2_b2, bn2_g, bn2_b, bn2_m, bn2_v,
                                       fc1_W, fc1_b, fc2_W, fc2_b, out);
}